// Round 13
// baseline (189.819 us; speedup 1.0000x reference)
//
#include <hip/hip_runtime.h>

#define FDIM 128
#define UDIM 128
#define BROWS 32             // rows per bucket
#define CAP   1408           // max edges/bucket (mean 1056, sigma ~33 -> +10.7s)
#define TILE  4096           // edges per bin tile
#define EPT   16             // edges per thread in bin tile
#define NPAIR 4              // feature slab-pairs: 32 feats = 64 B/row, 3.2 MB/pair
#define NTMAX 512            // max bin tiles (403 actual)

typedef __attribute__((ext_vector_type(8))) short short8;   // 8 bf16
typedef __attribute__((ext_vector_type(4))) float floatx4;  // mfma acc
typedef __attribute__((ext_vector_type(2))) float f32x2;    // packed f32 (v_pk_fma)

__device__ inline unsigned int round_bf16_bits(float a) {
  unsigned int ua = __float_as_uint(a);
  ua += 0x7fffu + ((ua >> 16) & 1u);
  return ua & 0xffff0000u;
}
__device__ inline unsigned int pack_bf16(float a, float b) {
  unsigned int ua = __float_as_uint(a);
  unsigned int ub = __float_as_uint(b);
  ua += 0x7fffu + ((ua >> 16) & 1u);
  ub += 0x7fffu + ((ub >> 16) & 1u);
  return (ua >> 16) | (ub & 0xffff0000u);
}

// ---------------------------------------------------------------------------
// block_scan_excl: exclusive scan of A[0..n) in place (A[n] = total).
// 256 threads; per-thread chunk is private (no cross-thread A hazard).
// ---------------------------------------------------------------------------
__device__ void block_scan_excl(int* A, int n, int* tpart, int* wtot) {
  int t = threadIdx.x;
  int per = (n + 255) >> 8;
  int s0 = t * per;
  int local = 0;
  for (int k = 0; k < per; ++k) {
    int i = s0 + k;
    if (i < n) local += A[i];
  }
  tpart[t] = local;
  __syncthreads();
  int lane = t & 63, w = t >> 6;
  int v = tpart[t];
  int incl = v;
  #pragma unroll
  for (int off = 1; off < 64; off <<= 1) {
    int u = __shfl_up(incl, off, 64);
    if (lane >= off) incl += u;
  }
  if (lane == 63) wtot[w] = incl;
  __syncthreads();
  int woff = 0;
  #pragma unroll
  for (int i = 0; i < 4; ++i) woff += (i < w) ? wtot[i] : 0;
  int excl = woff + incl - v;
  int run = excl;
  for (int k = 0; k < per; ++k) {
    int i = s0 + k;
    if (i < n) { int a = A[i]; A[i] = run; run += a; }
  }
  if (t == 255) A[n] = run;       // grand total
  __syncthreads();
}

// ---------------------------------------------------------------------------
// prep: zero diag and build kfrag (MFMA B-frags of K)
// ---------------------------------------------------------------------------
__global__ __launch_bounds__(256) void prep(
    const float* __restrict__ K, uint4* __restrict__ kfrag,
    int* __restrict__ zbase, int zcount) {
  int gid = blockIdx.x * 256 + threadIdx.x;
  if (gid < 2048) {
    int lane = gid & 63, bb = gid >> 6;
    int n = (bb >> 2) * 16 + (lane & 15);
    int k0 = (bb & 3) * 32 + (lane >> 4) * 8;
    unsigned int pq[4];
    #pragma unroll
    for (int j = 0; j < 4; ++j) {
      float a = K[(size_t)(k0 + 2 * j) * UDIM + n];
      float b = K[(size_t)(k0 + 2 * j + 1) * UDIM + n];
      pq[j] = pack_bf16(a, b);
    }
    kfrag[gid] = make_uint4(pq[0], pq[1], pq[2], pq[3]);
  }
  if (gid < zcount) zbase[gid] = 0;
}

// ---------------------------------------------------------------------------
// bin_dev: DETERMINISTIC tile-sorted binning (R12 lesson: per-edge 8 B
// scatter = 61 MB partial-line writeback at ~1.25 TB/s + 630 K contended
// cursor atomics -> 48.8 us at 6% VALU. Direct scatter can never coalesce:
// within-bucket runs exist in address space but not in time). Each block
// counting-sorts its 4096-edge tile by bucket in LDS, then writes THREE
// fully-coalesced streams: sorted4g (4 B/edge w|dst), key5g (1 B/edge row),
// sbg (per-tile bucket exclusive scan, 1564 ints). NO global atomics at all
// (except N diag self-loop adds) — each tile owns its region.
// ---------------------------------------------------------------------------
__device__ void bin_dev(int blk, const int* __restrict__ src,
                        const int* __restrict__ dst, const float* __restrict__ w,
                        unsigned int* __restrict__ sorted4g,
                        unsigned char* __restrict__ key5g,
                        int* __restrict__ sbg, float* __restrict__ diag,
                        int E, int NB, char* smem) {
  int* scnt  = (int*)smem;                       // NB+1
  int* scur  = scnt + (NB + 1);                  // NB
  int* tpart = scur + NB;                        // 256
  int* wtot  = tpart + 256;                      // 8
  unsigned int* sord = (unsigned int*)(wtot + 8);        // TILE
  unsigned char* krow = (unsigned char*)(sord + TILE);   // TILE
  int t = threadIdx.x;
  for (int b = t; b <= NB; b += 256) scnt[b] = 0;
  __syncthreads();

  uint2 pay[EPT];
  int e0 = blk * TILE;
  #pragma unroll
  for (int j = 0; j < EPT; ++j) {
    int e = e0 + j * 256 + t;
    if (e < E) {
      int s = src[e];
      int d = dst[e];
      float wv = w[e];
      if (s == d) atomicAdd(&diag[s], wv);
      pay[j].x = round_bf16_bits(wv) | (unsigned int)d;
      pay[j].y = (unsigned int)s;
      atomicAdd(&scnt[s >> 5], 1);
    } else {
      pay[j].y = 0xffffffffu;
    }
  }
  __syncthreads();

  block_scan_excl(scnt, NB, tpart, wtot);        // scnt = exclusive starts

  for (int b = t; b < NB; b += 256) scur[b] = scnt[b];
  __syncthreads();

  #pragma unroll
  for (int j = 0; j < EPT; ++j) {
    if (pay[j].y != 0xffffffffu) {
      int b = (int)(pay[j].y >> 5);
      int pos = atomicAdd(&scur[b], 1);          // LDS atomic only
      sord[pos] = pay[j].x;
      krow[pos] = (unsigned char)(pay[j].y & 31u);
    }
  }
  __syncthreads();

  // fully coalesced writeout (tail-tile padding is garbage but unreferenced)
  unsigned int* s4 = sorted4g + (size_t)blk * TILE;
  #pragma unroll
  for (int i = 0; i < TILE / 256; ++i) s4[i * 256 + t] = sord[i * 256 + t];
  unsigned int* k4 = (unsigned int*)(key5g + (size_t)blk * TILE);
  #pragma unroll
  for (int i = 0; i < TILE / 1024; ++i)
    k4[i * 256 + t] = ((unsigned int*)krow)[i * 256 + t];
  int* sb = sbg + (size_t)blk * (NB + 1);
  for (int b = t; b <= NB; b += 256) sb[b] = scnt[b];
}

// ---------------------------------------------------------------------------
// gemm_dev: one 64-row MFMA tile of Y = X @ K (bf16 16x16x32). Epilogue
// writes PAIR-SLAB layout: Ybf[sp][r][32 feats], sp = wave; each pair is a
// contiguous N*64 B region (3.2 MB) = one XCD's L2 working set in
// gather_slab (R10-R12 measured: FETCH 169->33 MB).
// ---------------------------------------------------------------------------
__device__ void gemm_dev(int g, const float* __restrict__ x,
                         const uint4* __restrict__ kfrag,
                         unsigned short* __restrict__ Ybf, int N, char* smem) {
  unsigned short (*sX)[136] = (unsigned short (*)[136])smem;
  int t = threadIdx.x;
  int r0 = g * 64;

  #pragma unroll
  for (int i = 0; i < 8; ++i) {
    int li = i * 256 + t;
    int row = li >> 5;
    int col4 = (li & 31) * 4;
    int gr = r0 + row; if (gr > N - 1) gr = N - 1;
    float4 v = *(const float4*)(x + (size_t)gr * FDIM + col4);
    *(uint2*)(&sX[row][col4]) = make_uint2(pack_bf16(v.x, v.y), pack_bf16(v.z, v.w));
  }
  __syncthreads();

  int wave = t >> 6, lane = t & 63;
  int m = lane & 15, q = lane >> 4;

  short8 bf[2][4];
  #pragma unroll
  for (int c = 0; c < 2; ++c)
    #pragma unroll
    for (int ks = 0; ks < 4; ++ks)
      bf[c][ks] = *(const short8*)&kfrag[(size_t)((2 * wave + c) * 4 + ks) * 64 + lane];

  floatx4 acc[4][2];
  #pragma unroll
  for (int rt = 0; rt < 4; ++rt)
    #pragma unroll
    for (int c = 0; c < 2; ++c)
      acc[rt][c] = (floatx4){0.f, 0.f, 0.f, 0.f};

  #pragma unroll
  for (int ks = 0; ks < 4; ++ks) {
    #pragma unroll
    for (int rt = 0; rt < 4; ++rt) {
      short8 af = *(const short8*)&sX[rt * 16 + m][ks * 32 + q * 8];
      acc[rt][0] = __builtin_amdgcn_mfma_f32_16x16x32_bf16(af, bf[0][ks], acc[rt][0], 0, 0, 0);
      acc[rt][1] = __builtin_amdgcn_mfma_f32_16x16x32_bf16(af, bf[1][ks], acc[rt][1], 0, 0, 0);
    }
  }

  unsigned short* yp = Ybf + (size_t)wave * N * 32;   // pair slab sp = wave
  #pragma unroll
  for (int rt = 0; rt < 4; ++rt) {
    #pragma unroll
    for (int c = 0; c < 2; ++c) {
      int off = c * 16 + m;                  // within-pair column (0..31)
      #pragma unroll
      for (int reg = 0; reg < 4; ++reg) {
        int r = r0 + rt * 16 + q * 4 + reg;
        if (r < N)
          yp[(size_t)r * 32 + off] =
              (unsigned short)(round_bf16_bits(acc[rt][c][reg]) >> 16);
      }
    }
  }
}

// ---------------------------------------------------------------------------
// bin_gemm: heterogeneous dispatch; blocks [0,nbin) bin, rest do GEMM tiles.
// smem = bin's 34 KB (4 blocks/CU — fine: only 403 bin blocks = 1.6/CU).
// ---------------------------------------------------------------------------
__global__ __launch_bounds__(256) void bin_gemm(
    const int* __restrict__ src, const int* __restrict__ dst,
    const float* __restrict__ w,
    unsigned int* __restrict__ sorted4g, unsigned char* __restrict__ key5g,
    int* __restrict__ sbg, float* __restrict__ diag,
    const float* __restrict__ x, const uint4* __restrict__ kfrag,
    unsigned short* __restrict__ Ybf, int N, int E, int NB, int nbin) {
  __shared__ alignas(16) char smem[34048];   // bin 34 KB > gemm 17.4 KB
  if (blockIdx.x < (unsigned)nbin)
    bin_dev(blockIdx.x, src, dst, w, sorted4g, key5g, sbg, diag, E, NB, smem);
  else
    gemm_dev(blockIdx.x - nbin, x, kfrag, Ybf, N, smem);
}

// ---------------------------------------------------------------------------
// sortk: indexed-merge front-end (reads each tile's segment for this bucket
// via sbg — moves the old scattered-WRITE cost to cheap L2/L3 reads) + the
// proven row-sort machinery (R12): scan32, length-rank bitonic permutation,
// row-grouped scatter, dscale precompute. Output format unchanged -> gather
// is byte-identical.
// ---------------------------------------------------------------------------
__global__ __launch_bounds__(256) void sortk(
    const unsigned int* __restrict__ sorted4g, const unsigned char* __restrict__ key5g,
    const int* __restrict__ sbg,
    unsigned int* __restrict__ sortedg, int* __restrict__ rstartg,
    int* __restrict__ permg,
    const float* __restrict__ diag, const float* __restrict__ x,
    float4* __restrict__ dscaleg, int N, int NB, int NT) {
  __shared__ unsigned int sdstw[CAP];      // 5632 B
  __shared__ unsigned int sorted[CAP];     // 5632 B
  __shared__ unsigned char skey[CAP];      // 1408 B
  __shared__ int kcnt[BROWS];
  __shared__ int rstart[BROWS + 1];
  __shared__ int mlen[NTMAX + 1];
  __shared__ int tpart[256];
  __shared__ int wtot[8];
  int b = blockIdx.x;
  int t = threadIdx.x;

  if (t < BROWS) {
    kcnt[t] = 0;
    int g = b * BROWS + t;                 // dscale precompute (diag is final)
    if (g < N) {
      float dg = diag[g];
      dscaleg[g] = make_float4(dg * x[(size_t)g * FDIM + 0],
                               dg * x[(size_t)g * FDIM + 5],
                               dg * x[(size_t)g * FDIM + 17],
                               dg * x[(size_t)g * FDIM + 42]);
    }
  }

  // merge index: segment length of this bucket in each tile
  for (int tt = t; tt < NT; tt += 256) {
    const int* sb = sbg + (size_t)tt * (NB + 1) + b;
    mlen[tt] = sb[1] - sb[0];
  }
  __syncthreads();
  block_scan_excl(mlen, NT, tpart, wtot);  // mlen[tt] = dest offset; [NT]=total
  int cntE = mlen[NT]; if (cntE > CAP) cntE = CAP;

  // copy segments into LDS + row histogram
  for (int tt = t; tt < NT; tt += 256) {
    int s0 = sbg[(size_t)tt * (NB + 1) + b];
    int dofs = mlen[tt];
    int len = mlen[tt + 1] - mlen[tt];
    const unsigned int* s4 = sorted4g + (size_t)tt * TILE + s0;
    const unsigned char* k5 = key5g + (size_t)tt * TILE + s0;
    for (int k = 0; k < len; ++k) {
      int pos = dofs + k;
      if (pos < CAP) {
        unsigned char ky = k5[k];
        sdstw[pos] = s4[k];
        skey[pos] = ky;
        atomicAdd(&kcnt[ky], 1);
      }
    }
  }
  __syncthreads();

  if (t < 64) {                            // wave 0 only
    int v = (t < BROWS) ? kcnt[t] : 0;
    if (t < BROWS) {
      int incl = v;
      #pragma unroll
      for (int off = 1; off < BROWS; off <<= 1) {
        int u = __shfl_up(incl, off, 64);
        if (t >= off) incl += u;
      }
      rstart[t + 1] = incl;
      kcnt[t] = incl - v;
      if (t == 0) rstart[0] = 0;
    }
    // descending bitonic sort of (count<<6|row) across lanes 0-31
    int lane = t;
    int key = (t < BROWS) ? ((v << 6) | t) : -1;
    #pragma unroll
    for (int k = 2; k <= 32; k <<= 1) {
      #pragma unroll
      for (int j = k >> 1; j > 0; j >>= 1) {
        int other = __shfl_xor(key, j, 64);
        bool up = ((lane & k) == 0);
        bool takeBig = ((lane & j) == 0);
        bool keep = up ? (takeBig ? key >= other : key <= other)
                       : (takeBig ? key <= other : key >= other);
        key = keep ? key : other;
      }
    }
    if (t < BROWS) permg[b * BROWS + t] = key & 63;   // rank t -> row
  }
  __syncthreads();

  for (int e = t; e < cntE; e += 256) {
    int k = skey[e];
    int pos = atomicAdd(&kcnt[k], 1);
    sorted[pos] = sdstw[e];
  }
  __syncthreads();

  unsigned int* sg = sortedg + (size_t)b * CAP;
  for (int e = t; e < cntE; e += 256) sg[e] = sorted[e];   // coalesced
  if (t < BROWS + 1) rstartg[b * (BROWS + 1) + t] = rstart[t];
}

// ---------------------------------------------------------------------------
// gather_slab: XCD-local pair-slab gather — unchanged from R12 (locality
// proven: FETCH 33 MB; length-rank rows, packed f32x2 FMA, vectorized stage).
// ---------------------------------------------------------------------------
__global__ __launch_bounds__(256, 8) void gather_slab(
    const unsigned short* __restrict__ Ybf, const unsigned int* __restrict__ sortedg,
    const int* __restrict__ rstartg, const int* __restrict__ permg,
    const float4* __restrict__ dscaleg,
    const float* __restrict__ K, const float* __restrict__ bias,
    float* __restrict__ out, int N) {
  __shared__ alignas(16) unsigned int srow[CAP];   // 5632 B
  __shared__ int rsl[BROWS + 1];
  __shared__ int sperm[BROWS];
  __shared__ float4 dsc[BROWS];            // 512 B
  int bi = blockIdx.x;
  int p = bi & 3;                          // pair id (XCD-local under RR)
  int b = bi >> 2;                         // bucket
  int t = threadIdx.x;
  int lane = t & 63, wave = t >> 6;
  int rs = lane >> 3;                      // row slot (8 per wave)
  int fp = lane & 7;                       // feat-quad lane (4 floats)

  if (t < BROWS + 1) rsl[t] = rstartg[b * (BROWS + 1) + t];
  if (t < BROWS) {
    sperm[t] = permg[b * BROWS + t];
    int gg = b * BROWS + t;
    dsc[t] = (gg < N) ? dscaleg[gg] : make_float4(0.f, 0.f, 0.f, 0.f);
  }
  __syncthreads();
  int cnt = rsl[BROWS];

  const unsigned int* sg = sortedg + (size_t)b * CAP;
  int nc4 = cnt >> 2;                      // vectorized stage
  for (int i = t; i < nc4; i += 256)
    ((uint4*)srow)[i] = ((const uint4*)sg)[i];
  for (int e = nc4 * 4 + t; e < cnt; e += 256) srow[e] = sg[e];
  __syncthreads();

  int r = sperm[wave * 8 + rs];            // rank -> row (length-clustered)
  int g = b * BROWS + r;
  const unsigned short* yp = Ybf + (size_t)p * N * 32;
  int base = rsl[r];
  int len = rsl[r + 1] - base;

  // wave-uniform trip count: max over the 8 row-slots (near-equal lengths)
  int ml = len;
  ml = max(ml, __shfl_xor(ml, 8, 64));
  ml = max(ml, __shfl_xor(ml, 16, 64));
  ml = max(ml, __shfl_xor(ml, 32, 64));

  f32x2 acc01 = {0.f, 0.f}, acc23 = {0.f, 0.f};
  for (int k = 0; k < ml; k += 2) {
    bool v0 = (k < len), v1 = (k + 1 < len);
    unsigned int w0 = srow[v0 ? base + k : 0];
    unsigned int w1 = srow[v1 ? base + k + 1 : 0];
    w0 = v0 ? w0 : 0u;                     // word 0: row 0, weight 0 (R3)
    w1 = v1 ? w1 : 0u;
    uint2 pk0 = *(const uint2*)(yp + (size_t)(w0 & 0xffffu) * 32 + fp * 4);
    uint2 pk1 = *(const uint2*)(yp + (size_t)(w1 & 0xffffu) * 32 + fp * 4);
    float wj0 = __uint_as_float(w0 & 0xffff0000u);
    float wj1 = __uint_as_float(w1 & 0xffff0000u);
    f32x2 wv0 = {wj0, wj0}, wv1 = {wj1, wj1};
    f32x2 a0 = {__uint_as_float(pk0.x << 16), __uint_as_float(pk0.x & 0xffff0000u)};
    f32x2 a1 = {__uint_as_float(pk0.y << 16), __uint_as_float(pk0.y & 0xffff0000u)};
    f32x2 b0 = {__uint_as_float(pk1.x << 16), __uint_as_float(pk1.x & 0xffff0000u)};
    f32x2 b1 = {__uint_as_float(pk1.y << 16), __uint_as_float(pk1.y & 0xffff0000u)};
    acc01 += wv0 * a0;
    acc23 += wv0 * a1;
    acc01 += wv1 * b0;
    acc23 += wv1 * b1;
  }

  if (g < N) {
    float4 acc = make_float4(acc01[0], acc01[1], acc23[0], acc23[1]);
    float4 ds = dsc[r];
    const int lf[4] = {0, 5, 17, 42};
    float dsv[4] = {ds.x, ds.y, ds.z, ds.w};
    #pragma unroll
    for (int tt = 0; tt < 4; ++tt) {
      float4 k4 = *(const float4*)(K + (size_t)lf[tt] * UDIM + p * 32 + fp * 4);
      acc.x -= dsv[tt] * k4.x; acc.y -= dsv[tt] * k4.y;
      acc.z -= dsv[tt] * k4.z; acc.w -= dsv[tt] * k4.w;
    }
    float4 b4 = *(const float4*)(bias + p * 32 + fp * 4);
    acc.x = fmaxf(acc.x + b4.x, 0.f);
    acc.y = fmaxf(acc.y + b4.y, 0.f);
    acc.z = fmaxf(acc.z + b4.z, 0.f);
    acc.w = fmaxf(acc.w + b4.w, 0.f);
    *(float4*)(out + (size_t)g * UDIM + p * 32 + fp * 4) = acc;
  }
}

extern "C" void kernel_launch(void* const* d_in, const int* in_sizes, int n_in,
                              void* d_out, int out_size, void* d_ws, size_t ws_size,
                              hipStream_t stream) {
  const float* x    = (const float*)d_in[0];
  const int*   esrc = (const int*)d_in[1];
  const int*   edst = (const int*)d_in[2];
  const float* ew   = (const float*)d_in[3];
  const float* K    = (const float*)d_in[4];
  const float* bias = (const float*)d_in[5];
  float* out = (float*)d_out;

  const int N = in_sizes[0] / FDIM;
  const int E = in_sizes[1];
  const int NB = (N + BROWS - 1) / BROWS;   // 1563 buckets
  const int NT = (E + TILE - 1) / TILE;     // 403 tiles

  // workspace (~36 MB): Ybf 12.8 + diag 0.2 + kfrag + sorted4g 6.6 +
  // key5g 1.65 + sbg 2.52 + sortedg 8.8 + rstartg 0.21 + permg 0.2 + dscale 0.8
  char* p = (char*)d_ws;
  unsigned short* Ybf = (unsigned short*)p; p += (size_t)N * UDIM * 2;
  float* diag  = (float*)p;         p += (size_t)N * 4;
  uint4* kfrag = (uint4*)p;         p += (size_t)32 * 64 * 16;
  unsigned int* sorted4g = (unsigned int*)p; p += (size_t)NT * TILE * 4;
  unsigned char* key5g = (unsigned char*)p;  p += (size_t)NT * TILE;
  int* sbg = (int*)p;               p += (size_t)NT * (NB + 1) * 4;
  unsigned int* sortedg = (unsigned int*)p; p += (size_t)NB * CAP * 4;
  int* rstartg = (int*)p;           p += (size_t)NB * (BROWS + 2) * 4;
  int* permg = (int*)p;             p += (size_t)NB * BROWS * 4;
  p = (char*)(((uintptr_t)p + 15) & ~(uintptr_t)15);       // align float4
  float4* dscaleg = (float4*)p;     p += (size_t)N * 16;

  const int nbin = NT;                      // 403
  const int ngemm = (N + 63) / 64;          // 782

  prep<<<(N + 255) / 256, 256, 0, stream>>>(K, kfrag, (int*)diag, N);
  bin_gemm<<<nbin + ngemm, 256, 0, stream>>>(
      esrc, edst, ew, sorted4g, key5g, sbg, diag, x, kfrag, Ybf, N, E, NB, nbin);
  sortk<<<NB, 256, 0, stream>>>(sorted4g, key5g, sbg, sortedg, rstartg, permg,
                                diag, x, dscaleg, N, NB, NT);
  gather_slab<<<NB * NPAIR, 256, 0, stream>>>(
      Ybf, sortedg, rstartg, permg, dscaleg, K, bias, out, N);
}

// Round 14
// 189.440 us; speedup vs baseline: 1.0020x; 1.0020x over previous
//
#include <hip/hip_runtime.h>

#define FDIM 128
#define UDIM 128
#define BROWS 32             // rows per bucket
#define CAP   1408           // max edges/bucket (mean 1056, sigma ~33 -> +10.7s)
#define TILE  8192           // edges per bin tile (R13: bigger tile -> longer
                             // per-bucket runs -> ~half the partial-line writeback)
#define NPAIR 4              // feature slab-pairs: 32 feats = 64 B/row, 3.2 MB/pair

typedef __attribute__((ext_vector_type(8))) short short8;   // 8 bf16
typedef __attribute__((ext_vector_type(4))) float floatx4;  // mfma acc
typedef __attribute__((ext_vector_type(2))) float f32x2;    // packed f32 (v_pk_fma)

__device__ inline unsigned int round_bf16_bits(float a) {
  unsigned int ua = __float_as_uint(a);
  ua += 0x7fffu + ((ua >> 16) & 1u);
  return ua & 0xffff0000u;
}
__device__ inline unsigned int pack_bf16(float a, float b) {
  unsigned int ua = __float_as_uint(a);
  unsigned int ub = __float_as_uint(b);
  ua += 0x7fffu + ((ua >> 16) & 1u);
  ub += 0x7fffu + ((ub >> 16) & 1u);
  return (ua >> 16) | (ub & 0xffff0000u);
}

// ---------------------------------------------------------------------------
// prep: zero diag+cursor (contiguous) and build kfrag (MFMA B-frags of K)
// ---------------------------------------------------------------------------
__global__ __launch_bounds__(256) void prep(
    const float* __restrict__ K, uint4* __restrict__ kfrag,
    int* __restrict__ zbase, int zcount) {
  int gid = blockIdx.x * 256 + threadIdx.x;
  if (gid < 2048) {
    int lane = gid & 63, bb = gid >> 6;
    int n = (bb >> 2) * 16 + (lane & 15);
    int k0 = (bb & 3) * 32 + (lane >> 4) * 8;
    unsigned int pq[4];
    #pragma unroll
    for (int j = 0; j < 4; ++j) {
      float a = K[(size_t)(k0 + 2 * j) * UDIM + n];
      float b = K[(size_t)(k0 + 2 * j + 1) * UDIM + n];
      pq[j] = pack_bf16(a, b);
    }
    kfrag[gid] = make_uint4(pq[0], pq[1], pq[2], pq[3]);
  }
  if (gid < zcount) zbase[gid] = 0;
}

// ---------------------------------------------------------------------------
// bin_dev: bucket = src >> 5, 8 B meta — R12-proven LDS-histogram form, now
// TWO-PHASE over a 8192-edge tile (R13 post-mortem: R12's 61 MB WRITE at
// ~1.25 TB/s was the bin limiter; amplification ~ blocks x buckets lines.
// 202 blocks halves line touches; re-reading edges (phase 1 counts src only,
// phase 2 re-reads src/dst/w and scatters) costs +13 MB coalesced reads and
// kills the pay[] register array. The R13 fully-sorted attempt is abandoned:
// its merge read side was just as line-fragmented as the write side it saved.)
// ---------------------------------------------------------------------------
__device__ void bin_dev(int blk, const int* __restrict__ src,
                        const int* __restrict__ dst, const float* __restrict__ w,
                        int* __restrict__ cursor, uint2* __restrict__ meta,
                        float* __restrict__ diag, int E, int NB, char* smem) {
  int* scnt  = (int*)smem;          // NB ints
  int* sbase = scnt + NB;
  int* scur  = sbase + NB;
  int t = threadIdx.x;
  for (int b = t; b < NB; b += 256) { scnt[b] = 0; scur[b] = 0; }
  __syncthreads();

  int e0 = blk * TILE;
  int eend = e0 + TILE; if (eend > E) eend = E;

  // phase 1: histogram (src only)
  for (int e = e0 + t; e < eend; e += 256)
    atomicAdd(&scnt[src[e] >> 5], 1);
  __syncthreads();

  // reserve contiguous per-bucket ranges
  for (int b = t; b < NB; b += 256) {
    int c = scnt[b];
    if (c) sbase[b] = b * CAP + atomicAdd(&cursor[b], c);
  }
  __syncthreads();

  // phase 2: re-read and scatter
  for (int e = e0 + t; e < eend; e += 256) {
    int s = src[e];
    int d = dst[e];
    float wv = w[e];
    if (s == d) atomicAdd(&diag[s], wv);
    int b = s >> 5;
    int r = atomicAdd(&scur[b], 1);
    int pos = sbase[b] + r;
    if (pos < (b + 1) * CAP)
      meta[pos] = make_uint2(round_bf16_bits(wv) | (unsigned int)d,
                             (unsigned int)(s & 31));
  }
}

// ---------------------------------------------------------------------------
// gemm_dev: one 64-row MFMA tile of Y = X @ K (bf16 16x16x32). Epilogue
// writes PAIR-SLAB layout: Ybf[sp][r][32 feats], sp = wave; each pair is a
// contiguous N*64 B region (3.2 MB) = one XCD's L2 working set in
// gather_slab (R10-R13 measured: FETCH 169->33 MB).
// ---------------------------------------------------------------------------
__device__ void gemm_dev(int g, const float* __restrict__ x,
                         const uint4* __restrict__ kfrag,
                         unsigned short* __restrict__ Ybf, int N, char* smem) {
  unsigned short (*sX)[136] = (unsigned short (*)[136])smem;
  int t = threadIdx.x;
  int r0 = g * 64;

  #pragma unroll
  for (int i = 0; i < 8; ++i) {
    int li = i * 256 + t;
    int row = li >> 5;
    int col4 = (li & 31) * 4;
    int gr = r0 + row; if (gr > N - 1) gr = N - 1;
    float4 v = *(const float4*)(x + (size_t)gr * FDIM + col4);
    *(uint2*)(&sX[row][col4]) = make_uint2(pack_bf16(v.x, v.y), pack_bf16(v.z, v.w));
  }
  __syncthreads();

  int wave = t >> 6, lane = t & 63;
  int m = lane & 15, q = lane >> 4;

  short8 bf[2][4];
  #pragma unroll
  for (int c = 0; c < 2; ++c)
    #pragma unroll
    for (int ks = 0; ks < 4; ++ks)
      bf[c][ks] = *(const short8*)&kfrag[(size_t)((2 * wave + c) * 4 + ks) * 64 + lane];

  floatx4 acc[4][2];
  #pragma unroll
  for (int rt = 0; rt < 4; ++rt)
    #pragma unroll
    for (int c = 0; c < 2; ++c)
      acc[rt][c] = (floatx4){0.f, 0.f, 0.f, 0.f};

  #pragma unroll
  for (int ks = 0; ks < 4; ++ks) {
    #pragma unroll
    for (int rt = 0; rt < 4; ++rt) {
      short8 af = *(const short8*)&sX[rt * 16 + m][ks * 32 + q * 8];
      acc[rt][0] = __builtin_amdgcn_mfma_f32_16x16x32_bf16(af, bf[0][ks], acc[rt][0], 0, 0, 0);
      acc[rt][1] = __builtin_amdgcn_mfma_f32_16x16x32_bf16(af, bf[1][ks], acc[rt][1], 0, 0, 0);
    }
  }

  unsigned short* yp = Ybf + (size_t)wave * N * 32;   // pair slab sp = wave
  #pragma unroll
  for (int rt = 0; rt < 4; ++rt) {
    #pragma unroll
    for (int c = 0; c < 2; ++c) {
      int off = c * 16 + m;                  // within-pair column (0..31)
      #pragma unroll
      for (int reg = 0; reg < 4; ++reg) {
        int r = r0 + rt * 16 + q * 4 + reg;
        if (r < N)
          yp[(size_t)r * 32 + off] =
              (unsigned short)(round_bf16_bits(acc[rt][c][reg]) >> 16);
      }
    }
  }
}

// ---------------------------------------------------------------------------
// bin_gemm: heterogeneous dispatch; blocks [0,nbin) bin, rest do GEMM tiles.
// ---------------------------------------------------------------------------
__global__ __launch_bounds__(256) void bin_gemm(
    const int* __restrict__ src, const int* __restrict__ dst,
    const float* __restrict__ w, int* __restrict__ cursor,
    uint2* __restrict__ meta, float* __restrict__ diag,
    const float* __restrict__ x, const uint4* __restrict__ kfrag,
    unsigned short* __restrict__ Ybf, int N, int E, int NB, int nbin) {
  __shared__ alignas(16) char smem[18816];   // max(bin 3*NB*4=18756, gemm 17408)
  if (blockIdx.x < (unsigned)nbin)
    bin_dev(blockIdx.x, src, dst, w, cursor, meta, diag, E, NB, smem);
  else
    gemm_dev(blockIdx.x - nbin, x, kfrag, Ybf, N, smem);
}

// ---------------------------------------------------------------------------
// sortk: per-bucket row-sort (R12-proven, reverted from R13's merge), output
// sortedg + rstartg; bitonic length-rank permutation permg; dscale precompute.
// ---------------------------------------------------------------------------
__global__ __launch_bounds__(256) void sortk(
    const uint2* __restrict__ meta, const int* __restrict__ cursor,
    unsigned int* __restrict__ sortedg, int* __restrict__ rstartg,
    int* __restrict__ permg,
    const float* __restrict__ diag, const float* __restrict__ x,
    float4* __restrict__ dscaleg, int N) {
  __shared__ unsigned int sdstw[CAP];      // 5632 B
  __shared__ unsigned int sorted[CAP];     // 5632 B
  __shared__ unsigned char skey[CAP];      // 1408 B
  __shared__ int kcnt[BROWS];
  __shared__ int rstart[BROWS + 1];
  int b = blockIdx.x;
  int t = threadIdx.x;
  int cntE = cursor[b]; if (cntE > CAP) cntE = CAP;
  const uint2* mb = meta + (size_t)b * CAP;

  if (t < BROWS) {
    kcnt[t] = 0;
    int g = b * BROWS + t;                 // dscale precompute (diag is final)
    if (g < N) {
      float dg = diag[g];
      dscaleg[g] = make_float4(dg * x[(size_t)g * FDIM + 0],
                               dg * x[(size_t)g * FDIM + 5],
                               dg * x[(size_t)g * FDIM + 17],
                               dg * x[(size_t)g * FDIM + 42]);
    }
  }
  __syncthreads();

  for (int e = t; e < cntE; e += 256) {
    uint2 m = mb[e];
    sdstw[e] = m.x;
    skey[e] = (unsigned char)m.y;
    atomicAdd(&kcnt[m.y & 31u], 1);
  }
  __syncthreads();

  if (t < 64) {                            // wave 0 only
    int v = (t < BROWS) ? kcnt[t] : 0;
    if (t < BROWS) {
      int incl = v;
      #pragma unroll
      for (int off = 1; off < BROWS; off <<= 1) {
        int u = __shfl_up(incl, off, 64);
        if (t >= off) incl += u;
      }
      rstart[t + 1] = incl;
      kcnt[t] = incl - v;
      if (t == 0) rstart[0] = 0;
    }
    // descending bitonic sort of (count<<6|row) across lanes 0-31
    int lane = t;
    int key = (t < BROWS) ? ((v << 6) | t) : -1;
    #pragma unroll
    for (int k = 2; k <= 32; k <<= 1) {
      #pragma unroll
      for (int j = k >> 1; j > 0; j >>= 1) {
        int other = __shfl_xor(key, j, 64);
        bool up = ((lane & k) == 0);
        bool takeBig = ((lane & j) == 0);
        bool keep = up ? (takeBig ? key >= other : key <= other)
                       : (takeBig ? key <= other : key >= other);
        key = keep ? key : other;
      }
    }
    if (t < BROWS) permg[b * BROWS + t] = key & 63;   // rank t -> row
  }
  __syncthreads();

  for (int e = t; e < cntE; e += 256) {
    int k = skey[e];
    int pos = atomicAdd(&kcnt[k], 1);
    sorted[pos] = sdstw[e];
  }
  __syncthreads();

  unsigned int* sg = sortedg + (size_t)b * CAP;
  for (int e = t; e < cntE; e += 256) sg[e] = sorted[e];   // coalesced
  if (t < BROWS + 1) rstartg[b * (BROWS + 1) + t] = rstart[t];
}

// ---------------------------------------------------------------------------
// gather_slab: XCD-local pair-slab gather (locality proven: FETCH 33 MB).
// R13 change: inner loop restored to the R0-proven 8-DEEP BATCH (8 srow
// reads -> 8 uint2 loads -> 8 packed-FMA groups) — R12's 2-deep loop held
// only 2 loads in flight (VALU 55%, latency exposed). Masked elements use
// word 0 (row 0 finite, weight 0 -> term exactly 0; R3 lesson). VGPR ~45
// fits (256,8)'s 64-cap, preserving 8-block residency.
// ---------------------------------------------------------------------------
__global__ __launch_bounds__(256, 8) void gather_slab(
    const unsigned short* __restrict__ Ybf, const unsigned int* __restrict__ sortedg,
    const int* __restrict__ rstartg, const int* __restrict__ permg,
    const float4* __restrict__ dscaleg,
    const float* __restrict__ K, const float* __restrict__ bias,
    float* __restrict__ out, int N) {
  __shared__ alignas(16) unsigned int srow[CAP];   // 5632 B
  __shared__ int rsl[BROWS + 1];
  __shared__ int sperm[BROWS];
  __shared__ float4 dsc[BROWS];            // 512 B
  int bi = blockIdx.x;
  int p = bi & 3;                          // pair id (XCD-local under RR)
  int b = bi >> 2;                         // bucket
  int t = threadIdx.x;
  int lane = t & 63, wave = t >> 6;
  int rs = lane >> 3;                      // row slot (8 per wave)
  int fp = lane & 7;                       // feat-quad lane (4 floats)

  if (t < BROWS + 1) rsl[t] = rstartg[b * (BROWS + 1) + t];
  if (t < BROWS) {
    sperm[t] = permg[b * BROWS + t];
    int gg = b * BROWS + t;
    dsc[t] = (gg < N) ? dscaleg[gg] : make_float4(0.f, 0.f, 0.f, 0.f);
  }
  __syncthreads();
  int cnt = rsl[BROWS];

  const unsigned int* sg = sortedg + (size_t)b * CAP;
  int nc4 = cnt >> 2;                      // vectorized stage
  for (int i = t; i < nc4; i += 256)
    ((uint4*)srow)[i] = ((const uint4*)sg)[i];
  for (int e = nc4 * 4 + t; e < cnt; e += 256) srow[e] = sg[e];
  __syncthreads();

  int r = sperm[wave * 8 + rs];            // rank -> row (length-clustered)
  int g = b * BROWS + r;
  const unsigned short* yp = Ybf + (size_t)p * N * 32;
  int base = rsl[r];
  int len = rsl[r + 1] - base;

  // wave-uniform trip count: max over the 8 row-slots (near-equal lengths)
  int ml = len;
  ml = max(ml, __shfl_xor(ml, 8, 64));
  ml = max(ml, __shfl_xor(ml, 16, 64));
  ml = max(ml, __shfl_xor(ml, 32, 64));

  f32x2 acc01 = {0.f, 0.f}, acc23 = {0.f, 0.f};
  for (int k = 0; k < ml; k += 8) {
    unsigned int wv[8];
    #pragma unroll
    for (int j = 0; j < 8; ++j) {
      int idx = k + j;
      unsigned int u = srow[(idx < len) ? base + idx : 0];
      wv[j] = (idx < len) ? u : 0u;        // word 0: row 0, weight 0 (R3)
    }
    uint2 pk[8];
    #pragma unroll
    for (int j = 0; j < 8; ++j)
      pk[j] = *(const uint2*)(yp + (size_t)(wv[j] & 0xffffu) * 32 + fp * 4);
    #pragma unroll
    for (int j = 0; j < 8; ++j) {
      float wj = __uint_as_float(wv[j] & 0xffff0000u);
      f32x2 wj2 = {wj, wj};
      f32x2 a0 = {__uint_as_float(pk[j].x << 16), __uint_as_float(pk[j].x & 0xffff0000u)};
      f32x2 a1 = {__uint_as_float(pk[j].y << 16), __uint_as_float(pk[j].y & 0xffff0000u)};
      acc01 += wj2 * a0;
      acc23 += wj2 * a1;
    }
  }

  if (g < N) {
    float4 acc = make_float4(acc01[0], acc01[1], acc23[0], acc23[1]);
    float4 ds = dsc[r];
    const int lf[4] = {0, 5, 17, 42};
    float dsv[4] = {ds.x, ds.y, ds.z, ds.w};
    #pragma unroll
    for (int tt = 0; tt < 4; ++tt) {
      float4 k4 = *(const float4*)(K + (size_t)lf[tt] * UDIM + p * 32 + fp * 4);
      acc.x -= dsv[tt] * k4.x; acc.y -= dsv[tt] * k4.y;
      acc.z -= dsv[tt] * k4.z; acc.w -= dsv[tt] * k4.w;
    }
    float4 b4 = *(const float4*)(bias + p * 32 + fp * 4);
    acc.x = fmaxf(acc.x + b4.x, 0.f);
    acc.y = fmaxf(acc.y + b4.y, 0.f);
    acc.z = fmaxf(acc.z + b4.z, 0.f);
    acc.w = fmaxf(acc.w + b4.w, 0.f);
    *(float4*)(out + (size_t)g * UDIM + p * 32 + fp * 4) = acc;
  }
}

extern "C" void kernel_launch(void* const* d_in, const int* in_sizes, int n_in,
                              void* d_out, int out_size, void* d_ws, size_t ws_size,
                              hipStream_t stream) {
  const float* x    = (const float*)d_in[0];
  const int*   esrc = (const int*)d_in[1];
  const int*   edst = (const int*)d_in[2];
  const float* ew   = (const float*)d_in[3];
  const float* K    = (const float*)d_in[4];
  const float* bias = (const float*)d_in[5];
  float* out = (float*)d_out;

  const int N = in_sizes[0] / FDIM;
  const int E = in_sizes[1];
  const int NB = (N + BROWS - 1) / BROWS;   // 1563 buckets

  // workspace (~41.5 MB): Ybf 12.8 + diag/cursor + kfrag + meta 17.6 +
  // sortedg 8.8 + rstartg 0.21 + permg 0.2 + dscale 0.8
  char* p = (char*)d_ws;
  unsigned short* Ybf = (unsigned short*)p; p += (size_t)N * UDIM * 2;
  float* diag  = (float*)p;         p += (size_t)N * 4;
  int*   cursor = (int*)p;          p += (size_t)NB * 4;
  uint4* kfrag = (uint4*)p;         p += (size_t)32 * 64 * 16;
  uint2* meta = (uint2*)p;          p += (size_t)NB * CAP * 8;
  unsigned int* sortedg = (unsigned int*)p; p += (size_t)NB * CAP * 4;
  int* rstartg = (int*)p;           p += (size_t)NB * (BROWS + 2) * 4;
  int* permg = (int*)p;             p += (size_t)NB * BROWS * 4;
  p = (char*)(((uintptr_t)p + 15) & ~(uintptr_t)15);       // align float4
  float4* dscaleg = (float4*)p;     p += (size_t)N * 16;

  const int nbin = (E + TILE - 1) / TILE;   // 202
  const int ngemm = (N + 63) / 64;          // 782

  prep<<<(N + NB + 255) / 256, 256, 0, stream>>>(K, kfrag, (int*)diag, N + NB);
  bin_gemm<<<nbin + ngemm, 256, 0, stream>>>(
      esrc, edst, ew, cursor, meta, diag, x, kfrag, Ybf, N, E, NB, nbin);
  sortk<<<NB, 256, 0, stream>>>(meta, cursor, sortedg, rstartg, permg,
                                diag, x, dscaleg, N);
  gather_slab<<<NB * NPAIR, 256, 0, stream>>>(
      Ybf, sortedg, rstartg, permg, dscaleg, K, bias, out, N);
}